// Round 1
// baseline (1373.085 us; speedup 1.0000x reference)
//
#include <hip/hip_runtime.h>

typedef __bf16 bf16x8 __attribute__((ext_vector_type(8)));
typedef __bf16 bf16x4 __attribute__((ext_vector_type(4)));
typedef float  f32x4  __attribute__((ext_vector_type(4)));

constexpr int BM  = 128;
constexpr int BN  = 128;
constexpr int BK  = 64;     // one group (128) spans exactly 2 K-tiles
constexpr int LDK = 72;     // padded LDS k-stride (144 B: 16B-aligned, bank-uniform)

// C = A(fp32->bf16) @ dequant4bit(B) + bias
// A = x [M,K] row-major fp32 ; qweight [K/8, N] int32 (8 nibbles along K)
// qzeros [K/128, N/8] int32 (8 nibbles along N) ; scales [K/128, N] fp32
__global__ __launch_bounds__(256, 2)
void gptq_gemm_fused(const float* __restrict__ X,
                     const unsigned int* __restrict__ QW,
                     const unsigned int* __restrict__ QZ,
                     const float* __restrict__ SC,
                     const float* __restrict__ BIAS,
                     float* __restrict__ OUT,
                     const int M, const int N, const int K)
{
    __shared__ __bf16 As[BM * LDK];   // As[m][k]
    __shared__ __bf16 Bs[BN * LDK];   // Bs[n][k]  (B transposed: contiguous k per row)

    const int tid = threadIdx.x;
    const int nTn = N / BN;
    const int m0  = (blockIdx.x / nTn) * BM;
    const int n0  = (blockIdx.x % nTn) * BN;

    const int lane = tid & 63;
    const int wave = tid >> 6;
    const int wm   = (wave >> 1) * 64;      // wave's 64x64 sub-tile
    const int wn   = (wave & 1) * 64;
    const int l15  = lane & 15;
    const int lk8  = (lane >> 4) * 8;       // k-chunk of this lane's fragment

    // A staging: thread t -> k-chunk of 4 floats at col a_kc, rows a_r0 + 16*i
    const int a_kc = (tid & 15) * 4;
    const int a_r0 = tid >> 4;
    // B staging: thread t -> output col b_c, qweight rows b_r0 + 2*i (i=0..3)
    const int b_c  = tid & 127;
    const int b_r0 = tid >> 7;
    const int N8   = N >> 3;

    f32x4 acc[4][4] = {};

    // staging registers (software pipeline: loads for tile kt+1 issue during compute of kt)
    float4 av[8];
    unsigned int bw[4];
    float scale, nzs;

    auto load_tile = [&](int kt_) {
        const int k0 = kt_ * BK;
        #pragma unroll
        for (int i = 0; i < 8; ++i)
            av[i] = *(const float4*)&X[(m0 + a_r0 + 16 * i) * K + k0 + a_kc];
        const int qr = k0 >> 3;
        #pragma unroll
        for (int i = 0; i < 4; ++i)
            bw[i] = QW[(qr + b_r0 + 2 * i) * N + n0 + b_c];
        const int g = k0 >> 7;                 // GROUP_SIZE = 128
        scale = SC[g * N + n0 + b_c];
        const unsigned int qzv = QZ[g * N8 + ((n0 + b_c) >> 3)];
        const int z = (qzv >> (((n0 + b_c) & 7) * 4)) & 15;
        nzs = (float)z * scale;                // W = w*scale - z*scale
    };

    load_tile(0);

    const int kTiles = K / BK;
    for (int kt = 0; kt < kTiles; ++kt) {
        __syncthreads();                       // prior compute done; safe to overwrite LDS

        // ---- write A tile (fp32 -> bf16) ----
        #pragma unroll
        for (int i = 0; i < 8; ++i) {
            bf16x4 v = { (__bf16)av[i].x, (__bf16)av[i].y,
                         (__bf16)av[i].z, (__bf16)av[i].w };
            *(bf16x4*)&As[(a_r0 + 16 * i) * LDK + a_kc] = v;
        }
        // ---- write B tile (dequant nibbles -> bf16, transposed) ----
        {
            const float s = scale, nz = nzs;
            #pragma unroll
            for (int i = 0; i < 4; ++i) {
                const unsigned int w32 = bw[i];
                bf16x8 v;
                #pragma unroll
                for (int j = 0; j < 8; ++j) {
                    const int w = (w32 >> (4 * j)) & 15;
                    v[j] = (__bf16)((float)w * s - nz);
                }
                *(bf16x8*)&Bs[b_c * LDK + (b_r0 + 2 * i) * 8] = v;
            }
        }
        __syncthreads();                       // tile visible

        if (kt + 1 < kTiles) load_tile(kt + 1);  // prefetch overlaps MFMA below

        // ---- compute: 2 k-steps of 16x16x32, 4x4 fragments per wave ----
        #pragma unroll
        for (int ks = 0; ks < 2; ++ks) {
            bf16x8 af[4], bfr[4];
            #pragma unroll
            for (int mi = 0; mi < 4; ++mi)
                af[mi] = *(bf16x8*)&As[(wm + mi * 16 + l15) * LDK + ks * 32 + lk8];
            #pragma unroll
            for (int ni = 0; ni < 4; ++ni)
                bfr[ni] = *(bf16x8*)&Bs[(wn + ni * 16 + l15) * LDK + ks * 32 + lk8];
            #pragma unroll
            for (int mi = 0; mi < 4; ++mi)
                #pragma unroll
                for (int ni = 0; ni < 4; ++ni)
                    acc[mi][ni] = __builtin_amdgcn_mfma_f32_16x16x32_bf16(
                        af[mi], bfr[ni], acc[mi][ni], 0, 0, 0);
        }
    }

    // ---- epilogue: +bias, fp32 store ----
    // C/D frag layout (m89-verified): col = lane&15, row = (lane>>4)*4 + reg
    const int cb = n0 + wn + l15;
    const int rb = m0 + wm + (lane >> 4) * 4;
    #pragma unroll
    for (int ni = 0; ni < 4; ++ni) {
        const float bv = BIAS[cb + ni * 16];
        #pragma unroll
        for (int mi = 0; mi < 4; ++mi) {
            #pragma unroll
            for (int r = 0; r < 4; ++r)
                OUT[(size_t)(rb + mi * 16 + r) * N + cb + ni * 16] = acc[mi][ni][r] + bv;
        }
    }
}

extern "C" void kernel_launch(void* const* d_in, const int* in_sizes, int n_in,
                              void* d_out, int out_size, void* d_ws, size_t ws_size,
                              hipStream_t stream) {
    const float*        x    = (const float*)d_in[0];
    const unsigned int* qw   = (const unsigned int*)d_in[1];
    const unsigned int* qz   = (const unsigned int*)d_in[2];
    const float*        sc   = (const float*)d_in[3];
    // d_in[4] = g_idx (always i/128; computed directly in-kernel)
    const float*        bias = (const float*)d_in[5];
    float*              out  = (float*)d_out;

    const int K = in_sizes[4];          // 4096 (g_idx length)
    const int N = in_sizes[5];          // 11008 (bias length)
    const int M = in_sizes[0] / K;      // 8192 tokens

    const dim3 grid((M / BM) * (N / BN));
    gptq_gemm_fused<<<grid, 256, 0, stream>>>(x, qw, qz, sc, bias, out, M, N, K);
}

// Round 2
// 1306.438 us; speedup vs baseline: 1.0510x; 1.0510x over previous
//
#include <hip/hip_runtime.h>

typedef __bf16 bf16x8 __attribute__((ext_vector_type(8)));
typedef __bf16 bf16x4 __attribute__((ext_vector_type(4)));
typedef float  f32x4  __attribute__((ext_vector_type(4)));

typedef __attribute__((address_space(3))) unsigned int        lds_u32_t;
typedef const __attribute__((address_space(1))) unsigned int  glob_u32_t;

// ==================== Kernel 1: x fp32 -> bf16 ====================
__global__ __launch_bounds__(256)
void cvt_x_bf16(const float* __restrict__ X, __bf16* __restrict__ XB, long long n8)
{
    long long i = (long long)blockIdx.x * 256 + threadIdx.x;
    if (i >= n8) return;
    const float4* src = (const float4*)X + 2 * i;
    float4 a = src[0], b = src[1];
    bf16x8 v = { (__bf16)a.x, (__bf16)a.y, (__bf16)a.z, (__bf16)a.w,
                 (__bf16)b.x, (__bf16)b.y, (__bf16)b.z, (__bf16)b.w };
    *(bf16x8*)(XB + 8 * i) = v;
}

// ==================== Kernel 2: dequant -> W^T bf16 [N][K] ====================
// tile: 256 n-rows x 64 k. Coalesced QW reads, LDS transpose (XOR chunk swizzle),
// coalesced 128B-row stores.
__global__ __launch_bounds__(256)
void dequant_wt(const unsigned int* __restrict__ QW,
                const unsigned int* __restrict__ QZ,
                const float* __restrict__ SC,
                __bf16* __restrict__ WT,
                const int N, const int K)
{
    __shared__ __bf16 T[256 * 64];            // [256 n][8 chunks of 16B], XOR-swizzled
    const int tid = threadIdx.x;
    const int nK  = K >> 6;
    const int n0  = (blockIdx.x / nK) * 256;
    const int k0  = (blockIdx.x % nK) * 64;

    const int n = n0 + tid;
    const int g = k0 >> 7;                    // GROUP_SIZE=128, constant over 64-k tile
    const float s = SC[g * N + n];
    const unsigned int qzv = QZ[g * (N >> 3) + (n >> 3)];
    const float nz = (float)((qzv >> ((n & 7) * 4)) & 15) * s;
    const int qr0 = k0 >> 3;

    #pragma unroll
    for (int i = 0; i < 8; ++i) {
        const unsigned int w32 = QW[(size_t)(qr0 + i) * N + n];
        bf16x8 v;
        #pragma unroll
        for (int j = 0; j < 8; ++j)
            v[j] = (__bf16)((float)((w32 >> (4 * j)) & 15) * s - nz);
        *(bf16x8*)((char*)T + tid * 128 + ((i ^ (tid & 7)) << 4)) = v;
    }
    __syncthreads();
    #pragma unroll
    for (int it = 0; it < 8; ++it) {
        const int r = it * 32 + (tid >> 3);
        const int c = tid & 7;
        bf16x8 v = *(bf16x8*)((char*)T + r * 128 + ((c ^ (r & 7)) << 4));
        *(bf16x8*)(WT + (size_t)(n0 + r) * K + k0 + c * 8) = v;
    }
}

// ==================== Kernel 3: bf16 B^T GEMM (m97 structure) ====================
// C[M,N] = A[M,K] @ B^T  (B stored [N][K]) + bias.  128x128 tile, BK=64, 4 waves.
// global_load_lds width=16, linear LDS dest + pre-swizzled global source,
// XOR-swizzled ds_read (T2 via m173 pattern). XCD-aware block swizzle (T1).
__global__ __launch_bounds__(256, 2)
void gemm_bt_bf16(const __bf16* __restrict__ A,
                  const __bf16* __restrict__ B,
                  const float* __restrict__ BIAS,
                  float* __restrict__ OUT,
                  const int M, const int N, const int K)
{
    __shared__ __bf16 As[128 * 64];
    __shared__ __bf16 Bs[128 * 64];

    const int tid  = threadIdx.x;
    const int lane = tid & 63;
    const int wave = tid >> 6;

    // XCD swizzle (bijective: launcher guarantees gridDim.x % 8 == 0)
    const int cpx = gridDim.x >> 3;
    int bid = blockIdx.x;
    bid = (bid & 7) * cpx + (bid >> 3);

    const int nTn = N >> 7;
    const int m0  = (bid / nTn) << 7;
    const int n0  = (bid % nTn) << 7;

    const int wm  = (wave >> 1) * 64;
    const int wn  = (wave & 1) * 64;
    const int l15 = lane & 15;
    const int lhi = lane >> 4;

    f32x4 acc[4][4] = {};

    const size_t abase = (size_t)m0 * K;
    const size_t bbase = (size_t)n0 * K;

    const int kTiles = K >> 6;
    for (int kt = 0; kt < kTiles; ++kt) {
        const int k0 = kt << 6;
        __syncthreads();                       // prior compute done
        #pragma unroll
        for (int i = 0; i < 4; ++i) {
            const int c   = tid + 256 * i;     // 16B chunk index (linear LDS slot)
            const int row = c >> 3;
            const int sc_ = (c & 7) ^ (row & 7);   // pre-swizzled global chunk
            __builtin_amdgcn_global_load_lds(
                (glob_u32_t*)(A + abase + (size_t)row * K + k0 + sc_ * 8),
                (lds_u32_t*)((char*)As + c * 16), 16, 0, 0);
            __builtin_amdgcn_global_load_lds(
                (glob_u32_t*)(B + bbase + (size_t)row * K + k0 + sc_ * 8),
                (lds_u32_t*)((char*)Bs + c * 16), 16, 0, 0);
        }
        __syncthreads();                       // vmcnt(0) drain + barrier: tile ready

        #pragma unroll
        for (int ks = 0; ks < 2; ++ks) {
            bf16x8 af[4], bfr[4];
            #pragma unroll
            for (int mi = 0; mi < 4; ++mi) {
                const int row = wm + mi * 16 + l15;
                const int ch  = (ks * 4 + lhi) ^ (row & 7);
                af[mi] = *(bf16x8*)((char*)As + row * 128 + (ch << 4));
            }
            #pragma unroll
            for (int ni = 0; ni < 4; ++ni) {
                const int row = wn + ni * 16 + l15;
                const int ch  = (ks * 4 + lhi) ^ (row & 7);
                bfr[ni] = *(bf16x8*)((char*)Bs + row * 128 + (ch << 4));
            }
            #pragma unroll
            for (int mi = 0; mi < 4; ++mi)
                #pragma unroll
                for (int ni = 0; ni < 4; ++ni)
                    acc[mi][ni] = __builtin_amdgcn_mfma_f32_16x16x32_bf16(
                        af[mi], bfr[ni], acc[mi][ni], 0, 0, 0);
        }
    }

    // epilogue: C/D layout col=lane&15, row=(lane>>4)*4+reg (m89-verified)
    const int cb = n0 + wn + l15;
    const int rb = m0 + wm + (lane >> 4) * 4;
    #pragma unroll
    for (int ni = 0; ni < 4; ++ni) {
        const float bv = BIAS[cb + ni * 16];
        #pragma unroll
        for (int mi = 0; mi < 4; ++mi)
            #pragma unroll
            for (int r = 0; r < 4; ++r)
                OUT[(size_t)(rb + mi * 16 + r) * N + cb + ni * 16] = acc[mi][ni][r] + bv;
    }
}

// ==================== Fallback: round-1 fused kernel (verified pass) ====================
constexpr int BM  = 128;
constexpr int BN  = 128;
constexpr int BK  = 64;
constexpr int LDK = 72;

__global__ __launch_bounds__(256, 2)
void gptq_gemm_fused(const float* __restrict__ X,
                     const unsigned int* __restrict__ QW,
                     const unsigned int* __restrict__ QZ,
                     const float* __restrict__ SC,
                     const float* __restrict__ BIAS,
                     float* __restrict__ OUT,
                     const int M, const int N, const int K)
{
    __shared__ __bf16 As[BM * LDK];
    __shared__ __bf16 Bs[BN * LDK];

    const int tid = threadIdx.x;
    const int nTn = N / BN;
    const int m0  = (blockIdx.x / nTn) * BM;
    const int n0  = (blockIdx.x % nTn) * BN;

    const int lane = tid & 63;
    const int wave = tid >> 6;
    const int wm   = (wave >> 1) * 64;
    const int wn   = (wave & 1) * 64;
    const int l15  = lane & 15;
    const int lk8  = (lane >> 4) * 8;

    const int a_kc = (tid & 15) * 4;
    const int a_r0 = tid >> 4;
    const int b_c  = tid & 127;
    const int b_r0 = tid >> 7;
    const int N8   = N >> 3;

    f32x4 acc[4][4] = {};
    float4 av[8];
    unsigned int bw[4];
    float scale, nzs;

    auto load_tile = [&](int kt_) {
        const int k0 = kt_ * BK;
        #pragma unroll
        for (int i = 0; i < 8; ++i)
            av[i] = *(const float4*)&X[(m0 + a_r0 + 16 * i) * K + k0 + a_kc];
        const int qr = k0 >> 3;
        #pragma unroll
        for (int i = 0; i < 4; ++i)
            bw[i] = QW[(qr + b_r0 + 2 * i) * N + n0 + b_c];
        const int g = k0 >> 7;
        scale = SC[g * N + n0 + b_c];
        const unsigned int qzv = QZ[g * N8 + ((n0 + b_c) >> 3)];
        const int z = (qzv >> (((n0 + b_c) & 7) * 4)) & 15;
        nzs = (float)z * scale;
    };

    load_tile(0);

    const int kTiles = K / BK;
    for (int kt = 0; kt < kTiles; ++kt) {
        __syncthreads();
        #pragma unroll
        for (int i = 0; i < 8; ++i) {
            bf16x4 v = { (__bf16)av[i].x, (__bf16)av[i].y,
                         (__bf16)av[i].z, (__bf16)av[i].w };
            *(bf16x4*)&As[(a_r0 + 16 * i) * LDK + a_kc] = v;
        }
        {
            const float s = scale, nz = nzs;
            #pragma unroll
            for (int i = 0; i < 4; ++i) {
                const unsigned int w32 = bw[i];
                bf16x8 v;
                #pragma unroll
                for (int j = 0; j < 8; ++j) {
                    const int w = (w32 >> (4 * j)) & 15;
                    v[j] = (__bf16)((float)w * s - nz);
                }
                *(bf16x8*)&Bs[b_c * LDK + (b_r0 + 2 * i) * 8] = v;
            }
        }
        __syncthreads();

        if (kt + 1 < kTiles) load_tile(kt + 1);

        #pragma unroll
        for (int ks = 0; ks < 2; ++ks) {
            bf16x8 af[4], bfr[4];
            #pragma unroll
            for (int mi = 0; mi < 4; ++mi)
                af[mi] = *(bf16x8*)&As[(wm + mi * 16 + l15) * LDK + ks * 32 + lk8];
            #pragma unroll
            for (int ni = 0; ni < 4; ++ni)
                bfr[ni] = *(bf16x8*)&Bs[(wn + ni * 16 + l15) * LDK + ks * 32 + lk8];
            #pragma unroll
            for (int mi = 0; mi < 4; ++mi)
                #pragma unroll
                for (int ni = 0; ni < 4; ++ni)
                    acc[mi][ni] = __builtin_amdgcn_mfma_f32_16x16x32_bf16(
                        af[mi], bfr[ni], acc[mi][ni], 0, 0, 0);
        }
    }

    const int cb = n0 + wn + l15;
    const int rb = m0 + wm + (lane >> 4) * 4;
    #pragma unroll
    for (int ni = 0; ni < 4; ++ni) {
        const float bv = BIAS[cb + ni * 16];
        #pragma unroll
        for (int mi = 0; mi < 4; ++mi)
            #pragma unroll
            for (int r = 0; r < 4; ++r)
                OUT[(size_t)(rb + mi * 16 + r) * N + cb + ni * 16] = acc[mi][ni][r] + bv;
    }
}

extern "C" void kernel_launch(void* const* d_in, const int* in_sizes, int n_in,
                              void* d_out, int out_size, void* d_ws, size_t ws_size,
                              hipStream_t stream) {
    const float*        x    = (const float*)d_in[0];
    const unsigned int* qw   = (const unsigned int*)d_in[1];
    const unsigned int* qz   = (const unsigned int*)d_in[2];
    const float*        sc   = (const float*)d_in[3];
    const float*        bias = (const float*)d_in[5];
    float*              out  = (float*)d_out;

    const int K = in_sizes[4];          // 4096 (g_idx length)
    const int N = in_sizes[5];          // 11008 (bias length)
    const int M = in_sizes[0] / K;      // 8192 tokens

    const size_t needA = (size_t)M * K * 2;
    const size_t needB = (size_t)N * K * 2;
    const int    nwg   = (M / 128) * (N / 128);
    const bool canSplit = (ws_size >= needA + needB) &&
                          (M % 128 == 0) && (N % 256 == 0) && (K % 128 == 0) &&
                          ((nwg & 7) == 0);

    if (canSplit) {
        __bf16* xb = (__bf16*)d_ws;
        __bf16* wt = (__bf16*)((char*)d_ws + needA);
        const long long n8 = (long long)M * K / 8;
        cvt_x_bf16<<<(int)((n8 + 255) / 256), 256, 0, stream>>>(x, xb, n8);
        dequant_wt<<<(N / 256) * (K / 64), 256, 0, stream>>>(qw, qz, sc, wt, N, K);
        gemm_bt_bf16<<<nwg, 256, 0, stream>>>(xb, wt, bias, out, M, N, K);
    } else {
        gptq_gemm_fused<<<nwg, 256, 0, stream>>>(x, qw, qz, sc, bias, out, M, N, K);
    }
}

// Round 3
// 1107.297 us; speedup vs baseline: 1.2400x; 1.1798x over previous
//
#include <hip/hip_runtime.h>

typedef __bf16 bf16x8 __attribute__((ext_vector_type(8)));
typedef __bf16 bf16x4 __attribute__((ext_vector_type(4)));
typedef float  f32x4  __attribute__((ext_vector_type(4)));

typedef __attribute__((address_space(3))) unsigned int        lds_u32_t;
typedef const __attribute__((address_space(1))) unsigned int  glob_u32_t;

// ==================== Kernel 1: x fp32 -> bf16 ====================
__global__ __launch_bounds__(256)
void cvt_x_bf16(const float* __restrict__ X, __bf16* __restrict__ XB, long long n8)
{
    long long i = (long long)blockIdx.x * 256 + threadIdx.x;
    if (i >= n8) return;
    const float4* src = (const float4*)X + 2 * i;
    float4 a = src[0], b = src[1];
    bf16x8 v = { (__bf16)a.x, (__bf16)a.y, (__bf16)a.z, (__bf16)a.w,
                 (__bf16)b.x, (__bf16)b.y, (__bf16)b.z, (__bf16)b.w };
    *(bf16x8*)(XB + 8 * i) = v;
}

// ==================== Kernel 2: dequant -> W^T bf16 [N][K] ====================
__global__ __launch_bounds__(256)
void dequant_wt(const unsigned int* __restrict__ QW,
                const unsigned int* __restrict__ QZ,
                const float* __restrict__ SC,
                __bf16* __restrict__ WT,
                const int N, const int K)
{
    __shared__ __bf16 T[256 * 64];
    const int tid = threadIdx.x;
    const int nK  = K >> 6;
    const int n0  = (blockIdx.x / nK) * 256;
    const int k0  = (blockIdx.x % nK) * 64;

    const int n = n0 + tid;
    const int g = k0 >> 7;
    const float s = SC[g * N + n];
    const unsigned int qzv = QZ[g * (N >> 3) + (n >> 3)];
    const float nz = (float)((qzv >> ((n & 7) * 4)) & 15) * s;
    const int qr0 = k0 >> 3;

    #pragma unroll
    for (int i = 0; i < 8; ++i) {
        const unsigned int w32 = QW[(size_t)(qr0 + i) * N + n];
        bf16x8 v;
        #pragma unroll
        for (int j = 0; j < 8; ++j)
            v[j] = (__bf16)((float)((w32 >> (4 * j)) & 15) * s - nz);
        *(bf16x8*)((char*)T + tid * 128 + ((i ^ (tid & 7)) << 4)) = v;
    }
    __syncthreads();
    #pragma unroll
    for (int it = 0; it < 8; ++it) {
        const int r = it * 32 + (tid >> 3);
        const int c = tid & 7;
        bf16x8 v = *(bf16x8*)((char*)T + r * 128 + ((c ^ (r & 7)) << 4));
        *(bf16x8*)(WT + (size_t)(n0 + r) * K + k0 + c * 8) = v;
    }
}

// ==================== Kernel 3: 256x256 8-phase bf16 B^T GEMM ====================
// Tiles: BM=BN=256, BK=64. 8 waves (2M x 4N), per-wave 128x64 out, acc[8][4].
// LDS 128 KiB dynamic: A0|A1|B0|B1 (32 KiB each; buffer = one K-tile).
// Schedule (race-free by construction):
//   iter i: phases 0-3 compute tile 2i (buf0), stage tile 2i+1 halves -> buf1
//           phases 4-7 compute tile 2i+1 (buf1), stage tile 2i+2 halves -> buf0
//   A buffer is only staged in the phase-epoch AFTER all its reads completed
//   (buf0 reads end at barrier B of p3; buf0 staging happens p4-p7).
//   Counted vmcnt(2) at p0/p4 only (T4); vmcnt(0) only in last-iter drain.

#define PH_READS(b, ks, mh)                                                        \
  {                                                                                \
    if ((mh) == 0) {                                                               \
      _Pragma("unroll")                                                            \
      for (int ni = 0; ni < 4; ++ni)                                               \
        bfr[ni] = *(const bf16x8*)(smem + 65536 + (b) * 32768 +                    \
                     (wnRow + ni * 16 + l15) * 128 + ((((ks)*4 + lhi) ^ l7) << 4));\
    }                                                                              \
    _Pragma("unroll")                                                              \
    for (int mi = 0; mi < 4; ++mi)                                                 \
      af[mi] = *(const bf16x8*)(smem + (b) * 32768 +                               \
                 (wmRow + ((mh)*4 + mi) * 16 + l15) * 128 +                        \
                 ((((ks)*4 + lhi) ^ l7) << 4));                                    \
  }

#define PH_MFMA(mh)                                                                \
  {                                                                                \
    asm volatile("s_waitcnt lgkmcnt(0)" ::: "memory");                             \
    __builtin_amdgcn_sched_barrier(0);                                             \
    __builtin_amdgcn_s_setprio(1);                                                 \
    _Pragma("unroll")                                                              \
    for (int mi = 0; mi < 4; ++mi)                                                 \
      _Pragma("unroll")                                                            \
      for (int ni = 0; ni < 4; ++ni)                                               \
        acc[(mh)*4 + mi][ni] = __builtin_amdgcn_mfma_f32_16x16x32_bf16(            \
            af[mi], bfr[ni], acc[(mh)*4 + mi][ni], 0, 0, 0);                       \
    __builtin_amdgcn_s_setprio(0);                                                 \
    __builtin_amdgcn_s_barrier();                                                  \
  }

__global__ __launch_bounds__(512, 2)
void gemm_bt_256(const __bf16* __restrict__ A,
                 const __bf16* __restrict__ B,
                 const float* __restrict__ BIAS,
                 float* __restrict__ OUT,
                 const int M, const int N, const int K)
{
    extern __shared__ char smem[];   // 131072 B

    const int tid  = threadIdx.x;
    const int lane = tid & 63;
    const int wave = tid >> 6;

    // XCD-aware bijective swizzle (launcher guarantees gridDim.x % 8 == 0)
    const int cpx = gridDim.x >> 3;
    int bid = blockIdx.x;
    bid = (bid & 7) * cpx + (bid >> 3);

    const int nTn = N >> 8;
    const int m0  = (bid / nTn) << 8;
    const int n0  = (bid % nTn) << 8;

    const int wmRow = (wave >> 2) * 128;
    const int wnRow = (wave & 3) * 64;
    const int l15   = lane & 15;
    const int lhi   = lane >> 4;
    const int l7    = l15 & 7;

    f32x4 acc[8][4] = {};
    bf16x8 af[4], bfr[4];

    const size_t Ks = (size_t)K;

    // stage one half-tile (128 rows x 64 cols bf16): 2 x 16B gload_lds per thread,
    // linear LDS dest + chunk-XOR pre-swizzled global source (T2, rule #21)
    auto stage_half = [&](const __bf16* src, int gRow0, int t, int ldsBase) {
        const size_t base = (size_t)gRow0 * Ks + (size_t)t * 64;
        #pragma unroll
        for (int j = 0; j < 2; ++j) {
            const int c   = tid + 512 * j;
            const int row = c >> 3;
            const int sc  = (c & 7) ^ (row & 7);
            __builtin_amdgcn_global_load_lds(
                (glob_u32_t*)(src + base + (size_t)row * Ks + sc * 8),
                (lds_u32_t*)(smem + ldsBase + c * 16), 16, 0, 0);
        }
    };
    auto stage_tile_half = [&](int t, int hh, int b) {
        if (hh < 2) stage_half(A, m0 + hh * 128, t, b * 32768 + hh * 16384);
        else        stage_half(B, n0 + (hh - 2) * 128, t,
                               65536 + b * 32768 + (hh - 2) * 16384);
    };

    // prologue: tile 0 -> buf0 (8 loads in flight)
    #pragma unroll
    for (int hh = 0; hh < 4; ++hh) stage_tile_half(0, hh, 0);

    const int kT    = K >> 6;
    const int nIter = kT >> 1;

    for (int i = 0; i < nIter; ++i) {
        const int t1   = 2 * i + 1;       // -> buf1, computed p4-7
        const int t2   = 2 * i + 2;       // -> buf0, computed next iter
        const bool more = (t2 < kT);

        // ---- p0 : buf0 ks0 lo ----
        stage_tile_half(t1, 0, 1);
        asm volatile("s_waitcnt vmcnt(2)" ::: "memory");
        __builtin_amdgcn_s_barrier();
        PH_READS(0, 0, 0); PH_MFMA(0);
        // ---- p1 : buf0 ks0 hi ----
        PH_READS(0, 0, 1);
        stage_tile_half(t1, 1, 1);
        __builtin_amdgcn_s_barrier();
        PH_MFMA(1);
        // ---- p2 : buf0 ks1 lo ----
        PH_READS(0, 1, 0);
        stage_tile_half(t1, 2, 1);
        __builtin_amdgcn_s_barrier();
        PH_MFMA(0);
        // ---- p3 : buf0 ks1 hi ----
        PH_READS(0, 1, 1);
        stage_tile_half(t1, 3, 1);
        __builtin_amdgcn_s_barrier();
        PH_MFMA(1);
        // ---- p4 : buf1 ks0 lo ----
        if (more) {
            stage_tile_half(t2, 0, 0);
            asm volatile("s_waitcnt vmcnt(2)" ::: "memory");
        } else {
            asm volatile("s_waitcnt vmcnt(0)" ::: "memory");
        }
        __builtin_amdgcn_s_barrier();
        PH_READS(1, 0, 0); PH_MFMA(0);
        // ---- p5 : buf1 ks0 hi ----
        PH_READS(1, 0, 1);
        if (more) stage_tile_half(t2, 1, 0);
        __builtin_amdgcn_s_barrier();
        PH_MFMA(1);
        // ---- p6 : buf1 ks1 lo ----
        PH_READS(1, 1, 0);
        if (more) stage_tile_half(t2, 2, 0);
        __builtin_amdgcn_s_barrier();
        PH_MFMA(0);
        // ---- p7 : buf1 ks1 hi ----
        PH_READS(1, 1, 1);
        if (more) stage_tile_half(t2, 3, 0);
        __builtin_amdgcn_s_barrier();
        PH_MFMA(1);
    }

    // epilogue: C/D layout col=lane&15, row=(lane>>4)*4+reg (m89-verified)
    const int cb = n0 + wnRow + l15;
    const int rb = m0 + wmRow + (lane >> 4) * 4;
    #pragma unroll
    for (int ni = 0; ni < 4; ++ni) {
        const float bv = BIAS[cb + ni * 16];
        #pragma unroll
        for (int mi = 0; mi < 8; ++mi)
            #pragma unroll
            for (int r = 0; r < 4; ++r)
                OUT[(size_t)(rb + mi * 16 + r) * N + cb + ni * 16] = acc[mi][ni][r] + bv;
    }
}

// ==================== Fallback: round-1 fused kernel (verified pass) ====================
constexpr int BM  = 128;
constexpr int BN  = 128;
constexpr int BK  = 64;
constexpr int LDK = 72;

__global__ __launch_bounds__(256, 2)
void gptq_gemm_fused(const float* __restrict__ X,
                     const unsigned int* __restrict__ QW,
                     const unsigned int* __restrict__ QZ,
                     const float* __restrict__ SC,
                     const float* __restrict__ BIAS,
                     float* __restrict__ OUT,
                     const int M, const int N, const int K)
{
    __shared__ __bf16 As[BM * LDK];
    __shared__ __bf16 Bs[BN * LDK];

    const int tid = threadIdx.x;
    const int nTn = N / BN;
    const int m0  = (blockIdx.x / nTn) * BM;
    const int n0  = (blockIdx.x % nTn) * BN;

    const int lane = tid & 63;
    const int wave = tid >> 6;
    const int wm   = (wave >> 1) * 64;
    const int wn   = (wave & 1) * 64;
    const int l15  = lane & 15;
    const int lk8  = (lane >> 4) * 8;

    const int a_kc = (tid & 15) * 4;
    const int a_r0 = tid >> 4;
    const int b_c  = tid & 127;
    const int b_r0 = tid >> 7;
    const int N8   = N >> 3;

    f32x4 acc[4][4] = {};
    float4 av[8];
    unsigned int bw[4];
    float scale, nzs;

    auto load_tile = [&](int kt_) {
        const int k0 = kt_ * BK;
        #pragma unroll
        for (int i = 0; i < 8; ++i)
            av[i] = *(const float4*)&X[(m0 + a_r0 + 16 * i) * K + k0 + a_kc];
        const int qr = k0 >> 3;
        #pragma unroll
        for (int i = 0; i < 4; ++i)
            bw[i] = QW[(qr + b_r0 + 2 * i) * N + n0 + b_c];
        const int g = k0 >> 7;
        scale = SC[g * N + n0 + b_c];
        const unsigned int qzv = QZ[g * N8 + ((n0 + b_c) >> 3)];
        const int z = (qzv >> (((n0 + b_c) & 7) * 4)) & 15;
        nzs = (float)z * scale;
    };

    load_tile(0);

    const int kTiles = K / BK;
    for (int kt = 0; kt < kTiles; ++kt) {
        __syncthreads();
        #pragma unroll
        for (int i = 0; i < 8; ++i) {
            bf16x4 v = { (__bf16)av[i].x, (__bf16)av[i].y,
                         (__bf16)av[i].z, (__bf16)av[i].w };
            *(bf16x4*)&As[(a_r0 + 16 * i) * LDK + a_kc] = v;
        }
        {
            const float s = scale, nz = nzs;
            #pragma unroll
            for (int i = 0; i < 4; ++i) {
                const unsigned int w32 = bw[i];
                bf16x8 v;
                #pragma unroll
                for (int j = 0; j < 8; ++j) {
                    const int w = (w32 >> (4 * j)) & 15;
                    v[j] = (__bf16)((float)w * s - nz);
                }
                *(bf16x8*)&Bs[b_c * LDK + (b_r0 + 2 * i) * 8] = v;
            }
        }
        __syncthreads();

        if (kt + 1 < kTiles) load_tile(kt + 1);

        #pragma unroll
        for (int ks = 0; ks < 2; ++ks) {
            bf16x8 af[4], bfr[4];
            #pragma unroll
            for (int mi = 0; mi < 4; ++mi)
                af[mi] = *(bf16x8*)&As[(wm + mi * 16 + l15) * LDK + ks * 32 + lk8];
            #pragma unroll
            for (int ni = 0; ni < 4; ++ni)
                bfr[ni] = *(bf16x8*)&Bs[(wn + ni * 16 + l15) * LDK + ks * 32 + lk8];
            #pragma unroll
            for (int mi = 0; mi < 4; ++mi)
                #pragma unroll
                for (int ni = 0; ni < 4; ++ni)
                    acc[mi][ni] = __builtin_amdgcn_mfma_f32_16x16x32_bf16(
                        af[mi], bfr[ni], acc[mi][ni], 0, 0, 0);
        }
    }

    const int cb = n0 + wn + l15;
    const int rb = m0 + wm + (lane >> 4) * 4;
    #pragma unroll
    for (int ni = 0; ni < 4; ++ni) {
        const float bv = BIAS[cb + ni * 16];
        #pragma unroll
        for (int mi = 0; mi < 4; ++mi)
            #pragma unroll
            for (int r = 0; r < 4; ++r)
                OUT[(size_t)(rb + mi * 16 + r) * N + cb + ni * 16] = acc[mi][ni][r] + bv;
    }
}

extern "C" void kernel_launch(void* const* d_in, const int* in_sizes, int n_in,
                              void* d_out, int out_size, void* d_ws, size_t ws_size,
                              hipStream_t stream) {
    const float*        x    = (const float*)d_in[0];
    const unsigned int* qw   = (const unsigned int*)d_in[1];
    const unsigned int* qz   = (const unsigned int*)d_in[2];
    const float*        sc   = (const float*)d_in[3];
    const float*        bias = (const float*)d_in[5];
    float*              out  = (float*)d_out;

    const int K = in_sizes[4];          // 4096 (g_idx length)
    const int N = in_sizes[5];          // 11008 (bias length)
    const int M = in_sizes[0] / K;      // 8192 tokens

    const size_t needA = (size_t)M * K * 2;
    const size_t needB = (size_t)N * K * 2;
    const int    nwg   = (M / 256) * (N / 256);
    const bool canSplit = (ws_size >= needA + needB) &&
                          (M % 256 == 0) && (N % 256 == 0) && (K % 128 == 0) &&
                          ((nwg & 7) == 0);

    if (canSplit) {
        __bf16* xb = (__bf16*)d_ws;
        __bf16* wt = (__bf16*)((char*)d_ws + needA);
        const long long n8 = (long long)M * K / 8;
        cvt_x_bf16<<<(int)((n8 + 255) / 256), 256, 0, stream>>>(x, xb, n8);
        dequant_wt<<<(N / 256) * (K / 64), 256, 0, stream>>>(qw, qz, sc, wt, N, K);
        (void)hipFuncSetAttribute((const void*)gemm_bt_256,
                                  hipFuncAttributeMaxDynamicSharedMemorySize, 131072);
        gemm_bt_256<<<nwg, 512, 131072, stream>>>(xb, wt, bias, out, M, N, K);
    } else {
        const int nwg128 = (M / 128) * (N / 128);
        gptq_gemm_fused<<<nwg128, 256, 0, stream>>>(x, qw, qz, sc, bias, out, M, N, K);
    }
}